// Round 18
// baseline (512.003 us; speedup 1.0000x reference)
//
#include <hip/hip_runtime.h>
#include <hip/hip_bf16.h>

typedef unsigned short u16;
typedef float f32x4 __attribute__((ext_vector_type(4)));
typedef __bf16 bf16x8 __attribute__((ext_vector_type(8)));
typedef unsigned short u16x8 __attribute__((ext_vector_type(8)));
typedef unsigned short u16x4 __attribute__((ext_vector_type(4)));

__device__ __forceinline__ u16 f2bf(float f) {
    unsigned int u = __builtin_bit_cast(unsigned int, f);
    u += 0x7fffu + ((u >> 16) & 1u);   // RNE
    return (u16)(u >> 16);
}
__device__ __forceinline__ float bf2f(u16 h) {
    unsigned int u = ((unsigned int)h) << 16;
    return __builtin_bit_cast(float, u);
}
__device__ __forceinline__ f32x4 mfma_bf16(u16x8 a, u16x8 b, f32x4 c) {
    return __builtin_amdgcn_mfma_f32_16x16x32_bf16(
        __builtin_bit_cast(bf16x8, a), __builtin_bit_cast(bf16x8, b), c, 0, 0, 0);
}
// async global->LDS, 16B/lane; lds dest is wave-uniform base + lane*16
__device__ __forceinline__ void gload16(const void* g, void* l) {
    __builtin_amdgcn_global_load_lds(
        (const __attribute__((address_space(1))) unsigned int*)g,
        (__attribute__((address_space(3))) unsigned int*)l, 16, 0, 0);
}
// XCD-chunked bijective swizzle (T1, m157)
__device__ __forceinline__ int swz_bid(int hw, int nwg) {
    return (hw & 7) * (nwg >> 3) + (hw >> 3);
}
// exclusive prefix of ecnt[0..7] up to e (replaces scan_kernel dispatch; uniform scalar loads)
__device__ __forceinline__ int eoff_of(const int* __restrict__ ecnt, int e) {
    int s = 0;
    #pragma unroll
    for (int i = 0; i < 8; i++) if (i < e) s += ecnt[i];
    return s;
}

// ================= GEMM core: 128x128 tile, BK=64, 4 waves (2x2), single-buffer =================
template<bool GATHER>
__device__ __forceinline__ void gemm_core(
        const u16* __restrict__ Ab, const u16* __restrict__ Bb,
        int m0, int n0, int Klen, int Ksa, int Ksb, int cnt, const int* __restrict__ idx,
        u16* lds_a, u16* lds_b, f32x4 (&acc)[4][4]) {
    const int tid = threadIdx.x;
    const int w = tid >> 6, l = tid & 63;
    const int c8 = l & 7, r8 = l >> 3;          // 16B chunk, row-within-8
    const int lr = l & 15, lg = l >> 4;
    const int wr = (w >> 1) * 64, wc = (w & 1) * 64;
    const int swz = (c8 ^ r8) << 4;             // inverse-swizzled source byte offset

    const char* asrc[4];
    const char* bsrc[4];
    #pragma unroll
    for (int i = 0; i < 4; i++) {
        int row = w * 32 + i * 8 + r8;          // tile row 0..127
        int gr = m0 + row; if (gr > cnt - 1) gr = cnt - 1;   // clamp partial tiles
        if (GATHER) gr = idx[gr];
        asrc[i] = (const char*)Ab + (size_t)gr * Ksa * 2 + swz;
        bsrc[i] = (const char*)Bb + (size_t)(n0 + row) * Ksb * 2 + swz;
    }
    for (int k0 = 0; k0 < Klen; k0 += 64) {
        __syncthreads();
        #pragma unroll
        for (int i = 0; i < 4; i++) {
            gload16(asrc[i] + (size_t)k0 * 2, lds_a + (w * 32 + i * 8) * 64);
            gload16(bsrc[i] + (size_t)k0 * 2, lds_b + (w * 32 + i * 8) * 64);
        }
        __syncthreads();
        #pragma unroll
        for (int kk = 0; kk < 2; kk++) {
            u16x8 af[4], bfr[4];
            #pragma unroll
            for (int mi = 0; mi < 4; mi++) {
                int m = wr + mi * 16 + lr;
                af[mi] = *(const u16x8*)((const char*)lds_a + m * 128 + (((kk * 4 + lg) ^ (m & 7)) << 4));
            }
            #pragma unroll
            for (int ni = 0; ni < 4; ni++) {
                int n = wc + ni * 16 + lr;
                bfr[ni] = *(const u16x8*)((const char*)lds_b + n * 128 + (((kk * 4 + lg) ^ (n & 7)) << 4));
            }
            #pragma unroll
            for (int mi = 0; mi < 4; mi++)
                #pragma unroll
                for (int ni = 0; ni < 4; ni++)
                    acc[mi][ni] = mfma_bf16(af[mi], bfr[ni], acc[mi][ni]);
        }
    }
}

// ================= coalesced bf16 epilogue: LDS-bounce (fixes 2x DRAM write amplification) ======
__device__ __forceinline__ void epilogue_bf16(
        f32x4 (&acc)[4][4], const float* __restrict__ bias, float sc, bool relu,
        u16* __restrict__ dst, int ldc, int m0, int n0, int cnt, u16* lds) {
    const int tid = threadIdx.x, w = tid >> 6, l = tid & 63;
    const int lr = l & 15, lg = l >> 4, wr = (w >> 1) * 64, wc = (w & 1) * 64;
    const int lrow_base = (wr ? 16 : 0);
    #pragma unroll
    for (int mi = 0; mi < 4; mi++) {
        __syncthreads();   // lds free of gemm_core readers (1st iter) / prior stores done
        #pragma unroll
        for (int ni = 0; ni < 4; ni++) {
            int col = wc + ni * 16 + lr;
            float bv = bias[n0 + col];
            #pragma unroll
            for (int r = 0; r < 4; r++) {
                float v = (acc[mi][ni][r] + bv) * sc;
                if (relu) v = fmaxf(v, 0.f);
                lds[(lrow_base + lg * 4 + r) * 132 + col] = f2bf(v);
            }
        }
        __syncthreads();
        int lrow = tid >> 3;                 // 0..31
        int lcol = (tid & 7) * 16;           // 0,16,...,112
        int grow = m0 + (lrow < 16 ? mi * 16 + lrow : 64 + mi * 16 + (lrow - 16));
        if (grow < cnt) {
            u16x8 v0 = *(const u16x8*)&lds[lrow * 132 + lcol];
            u16x8 v1 = *(const u16x8*)&lds[lrow * 132 + lcol + 8];
            *(u16x8*)&dst[(size_t)grow * ldc + n0 + lcol] = v0;
            *(u16x8*)&dst[(size_t)grow * ldc + n0 + lcol + 8] = v1;
        }
    }
}

// ================= dense GEMM: per-slab A/B/bias/out =================
struct Slab5 { const u16* a; const u16* bt; const float* bias; u16* cb; float sc; };
struct Slabs5 { Slab5 s[5]; };

template<int MODE, int NSLAB>
__global__ __launch_bounds__(256, 3) void gemm_dense(
        Slabs5 P, const float* __restrict__ extra, float* __restrict__ Cf, int K) {
    __shared__ __align__(16) u16 lds_a[128 * 64];
    __shared__ __align__(16) u16 lds_b[128 * 64];
    const int gx = NSLAB * 8;
    int bx, by;
    if (NSLAB == 5) {
        // 2D-chunked XCD mapping (r16). Note r17: FETCH 107->98MB only — co-residency breadth
        // (96 blocks/XCD) bounds L2 locality regardless of mapping. Kept (mild win, free).
        const int c = (int)blockIdx.x + gx * (int)blockIdx.y;
        const int b2 = c / 160, o = c % 160;
        bx = (b2 & 1) * 20 + (o % 20);
        by = (b2 >> 1) * 8 + (o / 20);
    } else {
        const int lid = swz_bid((int)blockIdx.x + gx * (int)blockIdx.y, gx * 32);
        bx = lid % gx; by = lid / gx;
    }
    const int slab = (NSLAB == 1) ? 0 : (bx >> 3);
    const int n0 = ((NSLAB == 1) ? bx : (bx & 7)) * 128;
    const int m0 = by * 128;
    f32x4 acc[4][4];
    #pragma unroll
    for (int i = 0; i < 4; i++)
        #pragma unroll
        for (int j = 0; j < 4; j++) acc[i][j] = (f32x4){0.f, 0.f, 0.f, 0.f};

    gemm_core<false>(P.s[slab].a, P.s[slab].bt, m0, n0, K, K, K, 0x7fffffff, nullptr, lds_a, lds_b, acc);

    if (MODE == 2) {
        epilogue_bf16(acc, P.s[slab].bias, P.s[slab].sc, false,
                      P.s[slab].cb, 1024, m0, n0, 0x7fffffff, lds_a);
        return;
    }
    const int tid = threadIdx.x, w = tid >> 6, l = tid & 63;
    const int lr = l & 15, lg = l >> 4, wr = (w >> 1) * 64, wc = (w & 1) * 64;
    const float* bias = P.s[slab].bias;
    #pragma unroll
    for (int ni = 0; ni < 4; ni++) {
        int col = n0 + wc + ni * 16 + lr;
        float bv = bias[col];
        #pragma unroll
        for (int mi = 0; mi < 4; mi++) {
            #pragma unroll
            for (int r = 0; r < 4; r++) {
                int row = m0 + wr + mi * 16 + lg * 4 + r;
                float v = acc[mi][ni][r] + bv;
                size_t off = (size_t)row * 1024 + col;
                Cf[off] = v + extra[off];
            }
        }
    }
}

// ================= MoE expert GEMMs (eoff computed inline from ecnt; scan dispatch removed) =====
__global__ __launch_bounds__(256, 3) void gemm_moe1(
        const u16* __restrict__ XNb, const u16* __restrict__ W1b, const float* __restrict__ b1,
        u16* __restrict__ HB, const int* __restrict__ eidx,
        const int* __restrict__ ecnt) {
    __shared__ __align__(16) u16 lds_a[128 * 64];
    __shared__ __align__(16) u16 lds_b[128 * 64];
    const int lid = swz_bid((int)blockIdx.x + 16 * ((int)blockIdx.y + 32 * (int)blockIdx.z), 4096);
    const int bx = lid & 15, rem = lid >> 4;
    const int by = rem & 31, e = rem >> 5;
    const int cnt = ecnt[e];
    const int m0 = by * 128;
    if (m0 >= cnt) return;
    const int n0 = bx * 128;    // N = 2048
    const int* idx = eidx + e * 4096;
    f32x4 acc[4][4];
    #pragma unroll
    for (int i = 0; i < 4; i++)
        #pragma unroll
        for (int j = 0; j < 4; j++) acc[i][j] = (f32x4){0.f, 0.f, 0.f, 0.f};

    gemm_core<true>(XNb, W1b + (size_t)e * 2048 * 1024, m0, n0, 1024, 1024, 1024, cnt, idx, lds_a, lds_b, acc);

    epilogue_bf16(acc, b1 + (size_t)e * 2048, 1.f, true,
                  HB + (size_t)eoff_of(ecnt, e) * 2048, 2048, m0, n0, cnt, lds_a);
}

// moe2: compact output Y[8192][1024] bf16 (no atomics); combine kernel applies gates.
__global__ __launch_bounds__(256, 3) void gemm_moe2(
        const u16* __restrict__ HB, const u16* __restrict__ W2b, const float* __restrict__ b2,
        u16* __restrict__ Y,
        const int* __restrict__ ecnt) {
    __shared__ __align__(16) u16 lds_a[128 * 64];
    __shared__ __align__(16) u16 lds_b[128 * 64];
    const int lid = swz_bid((int)blockIdx.x + 8 * ((int)blockIdx.y + 32 * (int)blockIdx.z), 2048);
    const int bx = lid & 7, rem = lid >> 3;
    const int by = rem & 31, e = rem >> 5;
    const int cnt = ecnt[e];
    const int m0 = by * 128;
    if (m0 >= cnt) return;
    const int n0 = bx * 128;    // N = 1024
    const int eo = eoff_of(ecnt, e);
    const u16* Ae = HB + (size_t)eo * 2048;
    f32x4 acc[4][4];
    #pragma unroll
    for (int i = 0; i < 4; i++)
        #pragma unroll
        for (int j = 0; j < 4; j++) acc[i][j] = (f32x4){0.f, 0.f, 0.f, 0.f};

    gemm_core<false>(Ae, W2b + (size_t)e * 1024 * 2048, m0, n0, 2048, 2048, 2048, cnt, nullptr, lds_a, lds_b, acc);

    epilogue_bf16(acc, b2 + (size_t)e * 1024, 1.f, false,
                  Y + (size_t)eo * 1024, 1024, m0, n0, cnt, lds_a);
}

// combine: out[t] += g0*Y[slot0[t]] + g1*Y[slot1[t]]  (prefix of ecnt computed inline)
__global__ void combine_kernel(const float* __restrict__ g2, const int* __restrict__ slotmap,
                               const int* __restrict__ ecnt, const u16* __restrict__ Y,
                               float* __restrict__ out) {
    int eo[8];
    {
        int s = 0;
        #pragma unroll
        for (int e = 0; e < 8; e++) { eo[e] = s; s += ecnt[e]; }
    }
    int t = blockIdx.x * 4 + (threadIdx.x >> 6);
    int l = threadIdx.x & 63;
    int s0 = slotmap[t * 2], s1 = slotmap[t * 2 + 1];
    float g0 = g2[t * 2], g1 = g2[t * 2 + 1];
    int r0 = eo[s0 >> 16] + (s0 & 0xffff);
    int r1 = eo[s1 >> 16] + (s1 & 0xffff);
    const u16* y0 = Y + (size_t)r0 * 1024 + l * 16;
    const u16* y1 = Y + (size_t)r1 * 1024 + l * 16;
    float* op = out + (size_t)t * 1024 + l * 16;
    u16x8 a0 = *(const u16x8*)y0;
    u16x8 a1 = *(const u16x8*)(y0 + 8);
    u16x8 b0 = *(const u16x8*)y1;
    u16x8 b1 = *(const u16x8*)(y1 + 8);
    f32x4 o[4];
    #pragma unroll
    for (int j = 0; j < 4; j++) o[j] = *(const f32x4*)(op + j * 4);
    #pragma unroll
    for (int j = 0; j < 4; j++) {
        o[0][j] += g0 * bf2f(a0[j])     + g1 * bf2f(b0[j]);
        o[1][j] += g0 * bf2f(a0[j + 4]) + g1 * bf2f(b0[j + 4]);
        o[2][j] += g0 * bf2f(a1[j])     + g1 * bf2f(b1[j]);
        o[3][j] += g0 * bf2f(a1[j + 4]) + g1 * bf2f(b1[j + 4]);
    }
    #pragma unroll
    for (int j = 0; j < 4; j++) *(f32x4*)(op + j * 4) = o[j];
}

// ================= LayerNorm (ln1/ln2: bf16 out) =================
__global__ void ln_kernel(const float* __restrict__ X, const float* __restrict__ g,
                          const float* __restrict__ bt, u16* __restrict__ Yb) {
    int row = blockIdx.x * 4 + (threadIdx.x >> 6);
    int l = threadIdx.x & 63;
    const float* x = X + (size_t)row * 1024;
    f32x4 v[4];
    float s = 0.f, s2 = 0.f;
    #pragma unroll
    for (int i = 0; i < 4; i++) {
        v[i] = *reinterpret_cast<const f32x4*>(x + i * 256 + l * 4);
        #pragma unroll
        for (int j = 0; j < 4; j++) { s += v[i][j]; s2 += v[i][j] * v[i][j]; }
    }
    #pragma unroll
    for (int m = 1; m < 64; m <<= 1) { s += __shfl_xor(s, m); s2 += __shfl_xor(s2, m); }
    float mu = s * (1.f / 1024.f);
    float var = s2 * (1.f / 1024.f) - mu * mu;
    float rs = rsqrtf(var + 1e-5f);
    #pragma unroll
    for (int i = 0; i < 4; i++) {
        f32x4 gv = *reinterpret_cast<const f32x4*>(g + i * 256 + l * 4);
        f32x4 bv = *reinterpret_cast<const f32x4*>(bt + i * 256 + l * 4);
        u16x4 ob;
        #pragma unroll
        for (int j = 0; j < 4; j++) ob[j] = f2bf((v[i][j] - mu) * rs * gv[j] + bv[j]);
        *reinterpret_cast<u16x4*>(Yb + (size_t)row * 1024 + i * 256 + l * 4) = ob;
    }
}

// ================= ln3 fused with gate: bf16 out + fp64-accum top-2 routing =================
__global__ void ln_gate_kernel(const float* __restrict__ X, const float* __restrict__ g,
                               const float* __restrict__ bt, u16* __restrict__ Yb,
                               const float* __restrict__ GW,
                               float* __restrict__ g2, int* __restrict__ top2) {
    int row = blockIdx.x * 4 + (threadIdx.x >> 6);
    int l = threadIdx.x & 63;
    const float* x = X + (size_t)row * 1024;
    f32x4 v[4];
    float s = 0.f, s2 = 0.f;
    #pragma unroll
    for (int i = 0; i < 4; i++) {
        v[i] = *reinterpret_cast<const f32x4*>(x + i * 256 + l * 4);
        #pragma unroll
        for (int j = 0; j < 4; j++) { s += v[i][j]; s2 += v[i][j] * v[i][j]; }
    }
    #pragma unroll
    for (int m = 1; m < 64; m <<= 1) { s += __shfl_xor(s, m); s2 += __shfl_xor(s2, m); }
    float mu = s * (1.f / 1024.f);
    float var = s2 * (1.f / 1024.f) - mu * mu;
    float rs = rsqrtf(var + 1e-5f);
    double p[8] = {0, 0, 0, 0, 0, 0, 0, 0};
    #pragma unroll
    for (int i = 0; i < 4; i++) {
        f32x4 gv = *reinterpret_cast<const f32x4*>(g + i * 256 + l * 4);
        f32x4 bv = *reinterpret_cast<const f32x4*>(bt + i * 256 + l * 4);
        u16x4 ob;
        #pragma unroll
        for (int j = 0; j < 4; j++) {
            float o = (v[i][j] - mu) * rs * gv[j] + bv[j];
            ob[j] = f2bf(o);
            const float* gw = GW + (size_t)(i * 256 + l * 4 + j) * 8;
            #pragma unroll
            for (int e = 0; e < 8; e++) p[e] += (double)o * (double)gw[e];
        }
        *reinterpret_cast<u16x4*>(Yb + (size_t)row * 1024 + i * 256 + l * 4) = ob;
    }
    #pragma unroll
    for (int e = 0; e < 8; e++) {
        #pragma unroll
        for (int m = 1; m < 64; m <<= 1) p[e] += __shfl_xor(p[e], m);
    }
    if (l == 0) {
        int i0 = 0; double v0 = p[0];
        #pragma unroll
        for (int e = 1; e < 8; e++) if (p[e] > v0) { v0 = p[e]; i0 = e; }
        int i1 = -1; double v1 = -1e300;
        #pragma unroll
        for (int e = 0; e < 8; e++) if (e != i0 && p[e] > v1) { v1 = p[e]; i1 = e; }
        float ex = __expf((float)(v1 - v0));
        float ga = 1.f / (1.f + ex);
        float gb = ex * ga;
        g2[row * 2] = ga; g2[row * 2 + 1] = gb;
        top2[row] = i0 | (i1 << 8);
    }
}

// ================= weight transpose+convert =================
struct Ptr8 { const float* p[8]; };
__global__ void wtrans_kernel(Ptr8 srcs, u16* __restrict__ dst, int K, int N) {
    __shared__ float t[64][65];
    const float* W = srcs.p[blockIdx.z];
    u16* Wt = dst + (size_t)blockIdx.z * K * N;
    int k0 = blockIdx.y * 64, n0 = blockIdx.x * 64;
    int tx = threadIdx.x, ty = threadIdx.y;
    #pragma unroll
    for (int i = 0; i < 8; i++) t[ty + i * 8][tx] = W[(size_t)(k0 + ty + i * 8) * N + n0 + tx];
    __syncthreads();
    #pragma unroll
    for (int i = 0; i < 8; i++) Wt[(size_t)(n0 + ty + i * 8) * K + k0 + tx] = f2bf(t[tx][ty + i * 8]);
}

// ================= flat fp32 -> bf16 =================
__global__ void cvt_kernel(const float* __restrict__ s, u16* __restrict__ d, int n) {
    int i = ((int)blockIdx.x * 256 + (int)threadIdx.x) * 8;
    if (i >= n) return;
    f32x4 a = *reinterpret_cast<const f32x4*>(s + i);
    f32x4 b = *reinterpret_cast<const f32x4*>(s + i + 4);
    u16x8 h;
    h[0] = f2bf(a[0]); h[1] = f2bf(a[1]); h[2] = f2bf(a[2]); h[3] = f2bf(a[3]);
    h[4] = f2bf(b[0]); h[5] = f2bf(b[1]); h[6] = f2bf(b[2]); h[7] = f2bf(b[3]);
    *reinterpret_cast<u16x8*>(d + i) = h;
}

// ================= V transpose (bf16) =================
__global__ void transpose_v(const u16* __restrict__ V, u16* __restrict__ Vt) {
    __shared__ u16 tile[32][34];
    int s0 = blockIdx.x * 32;
    int d0 = blockIdx.y * 32;
    int bh = blockIdx.z;
    int b = bh >> 4, h = bh & 15;
    int tx = threadIdx.x, ty = threadIdx.y;
    #pragma unroll
    for (int i = 0; i < 4; i++) {
        int s = s0 + ty + i * 8;
        tile[ty + i * 8][tx] = V[((size_t)s * 4 + b) * 1024 + h * 64 + d0 + tx];
    }
    __syncthreads();
    #pragma unroll
    for (int i = 0; i < 4; i++) {
        int d = d0 + ty + i * 8;
        Vt[((size_t)(bh * 64 + d)) * 1024 + s0 + tx] = tile[tx][ty + i * 8];
    }
}

// ================= flash attention (r16 body; attn is at its structural plateau) =================
template<bool CAUSAL>
__global__ __launch_bounds__(256, 4) void attn_kernel(
        const u16* __restrict__ Q, const u16* __restrict__ Km,
        const u16* __restrict__ Vt, u16* __restrict__ O) {
    __shared__ __align__(16) u16 kt_lds[64 * 64];
    __shared__ __align__(16) u16 vt_lds[64 * 64];
    __shared__ __align__(16) u16 p_lds[4][16 * 68];

    const int lid = swz_bid((int)blockIdx.x, 1024);
    int qt;
    if (CAUSAL) {
        const int i = lid & 15, j = (lid >> 5) & 3;
        qt = (((j & 1) ? (15 - i) : i) + ((j >> 1) << 3)) & 15;
    } else {
        qt = lid & 15;
    }
    const int hh = (lid >> 4) & 15;
    const int b  = lid >> 8;
    const int tid = threadIdx.x;
    const int w = tid >> 6, l = tid & 63;
    const int lr = l & 15, lg = l >> 4;
    const int c8 = l & 7, r8 = l >> 3;
    const int qb = qt * 64;

    u16x8 qf0, qf1;
    {
        const u16* qp = Q + ((size_t)(qb + w * 16 + lr) * 4 + b) * 1024 + hh * 64 + lg * 8;
        qf0 = *(const u16x8*)qp;
        qf1 = *(const u16x8*)(qp + 32);
    }
    const u16* kbase = Km + (size_t)b * 1024 + (size_t)hh * 64 + ((c8 ^ r8) << 3);
    const u16* vbase = Vt + ((size_t)(b * 16 + hh) * 64) * 1024 + ((c8 ^ r8) << 3);

    f32x4 o[4];
    #pragma unroll
    for (int ni = 0; ni < 4; ni++) o[ni] = (f32x4){0.f, 0.f, 0.f, 0.f};
    float Mr[4], Lr[4];
    #pragma unroll
    for (int r = 0; r < 4; r++) { Mr[r] = -1e30f; Lr[r] = 0.f; }

    const int nkt = CAUSAL ? (qt + 1) : 16;

    for (int kt = 0; kt < nkt; ++kt) {
        __syncthreads();   // all waves done reading previous tile
        #pragma unroll
        for (int i = 0; i < 2; i++) {
            int rrow = w * 16 + i * 8 + r8;
            gload16(kbase + (size_t)(kt * 64 + rrow) * 4096, &kt_lds[(w * 16 + i * 8) * 64]);
            gload16(vbase + (size_t)rrow * 1024 + kt * 64, &vt_lds[(w * 16 + i * 8) * 64]);
        }
        __syncthreads();   // implicit vmcnt(0) drain: tile ready

        f32x4 s4[4];
        __builtin_amdgcn_s_setprio(1);
        #pragma unroll
        for (int g = 0; g < 4; g++) {
            int krow = g * 16 + lr;
            const char* kl = (const char*)kt_lds + krow * 128;
            u16x8 kf0 = *(const u16x8*)(kl + ((lg ^ (krow & 7)) << 4));
            u16x8 kf1 = *(const u16x8*)(kl + (((lg + 4) ^ (krow & 7)) << 4));
            s4[g] = mfma_bf16(qf0, kf0, (f32x4){0.f, 0.f, 0.f, 0.f});
            s4[g] = mfma_bf16(qf1, kf1, s4[g]);
        }
        __builtin_amdgcn_s_setprio(0);
        if (CAUSAL && kt == qt) {
            #pragma unroll
            for (int g = 0; g < 4; g++) {
                int kg = kt * 64 + g * 16 + lr;
                #pragma unroll
                for (int r = 0; r < 4; r++) {
                    int qg = qb + w * 16 + lg * 4 + r;
                    if (kg > qg) s4[g][r] = -1e30f;
                }
            }
        }
        float mx[4];
        #pragma unroll
        for (int r = 0; r < 4; r++) {
            float m_ = fmaxf(fmaxf(s4[0][r], s4[1][r]), fmaxf(s4[2][r], s4[3][r]));
            m_ = fmaxf(m_, __shfl_xor(m_, 1));
            m_ = fmaxf(m_, __shfl_xor(m_, 2));
            m_ = fmaxf(m_, __shfl_xor(m_, 4));
            m_ = fmaxf(m_, __shfl_xor(m_, 8));
            mx[r] = m_;
        }
        bool fast = __all((mx[0] <= Mr[0] + 8.f) && (mx[1] <= Mr[1] + 8.f) &&
                          (mx[2] <= Mr[2] + 8.f) && (mx[3] <= Mr[3] + 8.f));
        #pragma unroll
        for (int r = 0; r < 4; r++) {
            if (!fast) {
                float newM = fmaxf(Mr[r], mx[r]);
                float corr = __expf(Mr[r] - newM);
                Lr[r] *= corr;
                o[0][r] *= corr; o[1][r] *= corr; o[2][r] *= corr; o[3][r] *= corr;
                Mr[r] = newM;
            }
            float p0 = __expf(s4[0][r] - Mr[r]);
            float p1 = __expf(s4[1][r] - Mr[r]);
            float p2 = __expf(s4[2][r] - Mr[r]);
            float p3 = __expf(s4[3][r] - Mr[r]);
            float ps = (p0 + p1) + (p2 + p3);
            ps += __shfl_xor(ps, 1); ps += __shfl_xor(ps, 2);
            ps += __shfl_xor(ps, 4); ps += __shfl_xor(ps, 8);
            Lr[r] += ps;
            int prow = lg * 4 + r;
            p_lds[w][prow * 68 + lr] = f2bf(p0);
            p_lds[w][prow * 68 + 16 + lr] = f2bf(p1);
            p_lds[w][prow * 68 + 32 + lr] = f2bf(p2);
            p_lds[w][prow * 68 + 48 + lr] = f2bf(p3);
        }
        asm volatile("s_waitcnt lgkmcnt(0)" ::: "memory");
        __builtin_amdgcn_s_setprio(1);
        #pragma unroll
        for (int kk = 0; kk < 2; kk++) {
            u16x8 pf = *(const u16x8*)&p_lds[w][lr * 68 + kk * 32 + lg * 8];
            #pragma unroll
            for (int ni = 0; ni < 4; ni++) {
                int vrow = ni * 16 + lr;
                const char* vl = (const char*)vt_lds + vrow * 128;
                u16x8 vf = *(const u16x8*)(vl + (((kk * 4 + lg) ^ (vrow & 7)) << 4));
                o[ni] = mfma_bf16(pf, vf, o[ni]);
            }
        }
        __builtin_amdgcn_s_setprio(0);
    }
    #pragma unroll
    for (int ni = 0; ni < 4; ni++) {
        #pragma unroll
        for (int r = 0; r < 4; r++) {
            int row = qb + w * 16 + lg * 4 + r;
            int col = ni * 16 + lr;
            O[((size_t)row * 4 + b) * 1024 + hh * 64 + col] = f2bf(o[ni][r] / Lr[r]);
        }
    }
}

// ================= build per-expert token lists + slot map =================
__global__ void build_lists(const int* __restrict__ top2, int* __restrict__ eidx,
                            int* __restrict__ ecnt, int* __restrict__ slotmap) {
    const int e = blockIdx.x;           // 8 blocks, one per expert
    const int tid = threadIdx.x;        // 256
    const int w = tid >> 6, l = tid & 63;
    __shared__ int wcnt[4];
    int base = 0;                       // maintained uniformly by all threads
    for (int c = 0; c < 4096; c += 256) {
        int tok = c + tid;
        int t2 = top2[tok];
        bool pf = ((t2 & 0xff) == e);
        bool ps = (((t2 >> 8) & 0xff) == e);
        bool pred = pf || ps;
        unsigned long long mask = __ballot(pred);
        if (l == 0) wcnt[w] = __popcll(mask);
        __syncthreads();
        int wb = base;
        for (int i = 0; i < w; i++) wb += wcnt[i];
        int pos = __popcll(mask & ((1ull << l) - 1ull));
        if (pred) {
            eidx[e * 4096 + wb + pos] = tok;
            slotmap[tok * 2 + (pf ? 0 : 1)] = (e << 16) | (wb + pos);
        }
        base += wcnt[0] + wcnt[1] + wcnt[2] + wcnt[3];
        __syncthreads();                // protect wcnt for next chunk
    }
    if (tid == 0) ecnt[e] = base;
}

// ================= launch =================
extern "C" void kernel_launch(void* const* d_in, const int* in_sizes, int n_in,
                              void* d_out, int out_size, void* d_ws, size_t ws_size,
                              hipStream_t stream) {
    const float* x    = (const float*)d_in[0];
    const float* enc  = (const float*)d_in[1];
    const float* ln1g = (const float*)d_in[3];
    const float* ln1b = (const float*)d_in[4];
    const float* ln2g = (const float*)d_in[5];
    const float* ln2b = (const float*)d_in[6];
    const float* ln3g = (const float*)d_in[7];
    const float* ln3b = (const float*)d_in[8];
    const float* saWq = (const float*)d_in[9];  const float* sabq = (const float*)d_in[10];
    const float* saWk = (const float*)d_in[11]; const float* sabk = (const float*)d_in[12];
    const float* saWv = (const float*)d_in[13]; const float* sabv = (const float*)d_in[14];
    const float* saWo = (const float*)d_in[15]; const float* sabo = (const float*)d_in[16];
    const float* caWq = (const float*)d_in[17]; const float* cabq = (const float*)d_in[18];
    const float* caWk = (const float*)d_in[19]; const float* cabk = (const float*)d_in[20];
    const float* caWv = (const float*)d_in[21]; const float* cabv = (const float*)d_in[22];
    const float* caWo = (const float*)d_in[23]; const float* cabo = (const float*)d_in[24];
    const float* gateW = (const float*)d_in[25];
    const float* W1 = (const float*)d_in[26]; const float* b1 = (const float*)d_in[27];
    const float* W2 = (const float*)d_in[28]; const float* b2 = (const float*)d_in[29];
    float* out = (float*)d_out;
    char* W = (char*)d_ws;

    const size_t MB = 1ull << 20;
    u16*   Wattn = (u16*)(W);                 // 0..16MB : 8 x [1024][1024] bf16 (B^T)
    u16*   Qb    = (u16*)(W + 16 * MB);       // 8MB
    u16*   Kb    = (u16*)(W + 24 * MB);       // 8MB
    u16*   Vb    = (u16*)(W + 32 * MB);       // 8MB
    u16*   VTb   = (u16*)(W + 40 * MB);       // 8MB
    u16*   ATb   = (u16*)(W + 48 * MB);       // 8MB
    u16*   encb  = (u16*)(W + 56 * MB);       // 8MB
    u16*   XNb   = (u16*)(W + 64 * MB);       // 8MB
    float* X1    = (float*)(W + 72 * MB);     // 16MB fp32 (SA residual out)
    u16*   K2b   = (u16*)(W + 88 * MB);       // 8MB (CA K; HB overlays later)
    u16*   V2b   = (u16*)(W + 96 * MB);       // 8MB (CA V)
    u16*   HB    = (u16*)(W + 88 * MB);       // 32MB: compact expert hidden (overlays K2b/V2b after CA)
    u16*   W1b   = (u16*)(W);                 // MoE: 0..32MB (overlays Wattn,Qb,Kb after CA-O)
    u16*   W2b   = (u16*)(W + 32 * MB);       // MoE: 32..64MB (overlays Vb,VTb,ATb,encb)
    u16*   Yc    = (u16*)(W);                 // 16MB compact moe2 out (overlays W1b, dead after moe1)
    float* g2    = (float*)(W + 120 * MB);              // 32KB (4096 x 2)
    int*   eidx  = (int*)(W + 120 * MB + 128 * 1024);   // 128KB
    int*   ecnt  = (int*)(W + 120 * MB + 256 * 1024);   // 64B
    int*   top2  = (int*)(W + 120 * MB + 272 * 1024);   // 16KB
    int*   slotmap = (int*)(W + 120 * MB + 320 * 1024); // 32KB

    dim3 bw(64, 8);
    const float SC = 0.125f;   // 1/sqrt(64) — power of two: lossless bf16 Q prescale (r12 lesson)

    {
        Ptr8 p; p.p[0]=saWq; p.p[1]=saWk; p.p[2]=saWv; p.p[3]=saWo;
                p.p[4]=caWq; p.p[5]=caWk; p.p[6]=caWv; p.p[7]=caWo;
        wtrans_kernel<<<dim3(16, 16, 8), bw, 0, stream>>>(p, Wattn, 1024, 1024);
    }
    cvt_kernel<<<2048, 256, 0, stream>>>(enc, encb, 4096 * 1024);

    // ---- self-attn QKV + cross-attn KV batched: 5 slabs, 1280 blocks (5/CU) ----
    ln_kernel<<<1024, 256, 0, stream>>>(x, ln1g, ln1b, XNb);
    {
        Slabs5 P;
        P.s[0] = {XNb,  Wattn,               sabq, Qb,  SC };
        P.s[1] = {XNb,  Wattn + 1 * 1048576, sabk, Kb,  1.f};
        P.s[2] = {XNb,  Wattn + 2 * 1048576, sabv, Vb,  1.f};
        P.s[3] = {encb, Wattn + 5 * 1048576, cabk, K2b, 1.f};
        P.s[4] = {encb, Wattn + 6 * 1048576, cabv, V2b, 1.f};
        gemm_dense<2, 5><<<dim3(40, 32), 256, 0, stream>>>(P, nullptr, nullptr, 1024);
    }
    transpose_v<<<dim3(32, 2, 64), dim3(32, 8), 0, stream>>>(Vb, VTb);
    attn_kernel<true><<<1024, 256, 0, stream>>>(Qb, Kb, VTb, ATb);
    {
        Slabs5 P; P.s[0] = {ATb, Wattn + 3 * 1048576, sabo, nullptr, 1.f};
        gemm_dense<1, 1><<<dim3(8, 32), 256, 0, stream>>>(P, x, X1, 1024);
    }

    // ---- cross-attention ----
    ln_kernel<<<1024, 256, 0, stream>>>(X1, ln2g, ln2b, XNb);
    {
        Slabs5 P; P.s[0] = {XNb, Wattn + 4 * 1048576, cabq, Qb, SC};
        gemm_dense<2, 1><<<dim3(8, 32), 256, 0, stream>>>(P, nullptr, nullptr, 1024);
    }
    transpose_v<<<dim3(32, 2, 64), dim3(32, 8), 0, stream>>>(V2b, VTb);
    attn_kernel<false><<<1024, 256, 0, stream>>>(Qb, K2b, VTb, ATb);
    {
        Slabs5 P; P.s[0] = {ATb, Wattn + 7 * 1048576, cabo, nullptr, 1.f};
        gemm_dense<1, 1><<<dim3(8, 32), 256, 0, stream>>>(P, X1, out, 1024);
    }

    // ---- MoE ----
    {
        Ptr8 p1; for (int e = 0; e < 8; e++) p1.p[e] = W1 + (size_t)e * 1024 * 2048;
        wtrans_kernel<<<dim3(32, 16, 8), bw, 0, stream>>>(p1, W1b, 1024, 2048);
        Ptr8 p2; for (int e = 0; e < 8; e++) p2.p[e] = W2 + (size_t)e * 2048 * 1024;
        wtrans_kernel<<<dim3(16, 32, 8), bw, 0, stream>>>(p2, W2b, 2048, 1024);
    }
    ln_gate_kernel<<<1024, 256, 0, stream>>>(out, ln3g, ln3b, XNb, gateW, g2, top2);
    build_lists<<<8, 256, 0, stream>>>(top2, eidx, ecnt, slotmap);
    gemm_moe1<<<dim3(16, 32, 8), 256, 0, stream>>>(XNb, W1b, b1, HB, eidx, ecnt);
    gemm_moe2<<<dim3(8, 32, 16) /*z=16 unused tail guarded by swz range*/, 256, 0, stream>>>(HB, W2b, b2, Yc, ecnt);
    combine_kernel<<<1024, 256, 0, stream>>>(g2, slotmap, ecnt, Yc, out);
}

// Round 19
// 475.498 us; speedup vs baseline: 1.0768x; 1.0768x over previous
//
#include <hip/hip_runtime.h>
#include <hip/hip_bf16.h>

typedef unsigned short u16;
typedef float f32x4 __attribute__((ext_vector_type(4)));
typedef __bf16 bf16x8 __attribute__((ext_vector_type(8)));
typedef unsigned short u16x8 __attribute__((ext_vector_type(8)));
typedef unsigned short u16x4 __attribute__((ext_vector_type(4)));

__device__ __forceinline__ u16 f2bf(float f) {
    unsigned int u = __builtin_bit_cast(unsigned int, f);
    u += 0x7fffu + ((u >> 16) & 1u);   // RNE
    return (u16)(u >> 16);
}
__device__ __forceinline__ float bf2f(u16 h) {
    unsigned int u = ((unsigned int)h) << 16;
    return __builtin_bit_cast(float, u);
}
__device__ __forceinline__ f32x4 mfma_bf16(u16x8 a, u16x8 b, f32x4 c) {
    return __builtin_amdgcn_mfma_f32_16x16x32_bf16(
        __builtin_bit_cast(bf16x8, a), __builtin_bit_cast(bf16x8, b), c, 0, 0, 0);
}
// async global->LDS, 16B/lane; lds dest is wave-uniform base + lane*16
__device__ __forceinline__ void gload16(const void* g, void* l) {
    __builtin_amdgcn_global_load_lds(
        (const __attribute__((address_space(1))) unsigned int*)g,
        (__attribute__((address_space(3))) unsigned int*)l, 16, 0, 0);
}
// XCD-chunked bijective swizzle (T1, m157)
__device__ __forceinline__ int swz_bid(int hw, int nwg) {
    return (hw & 7) * (nwg >> 3) + (hw >> 3);
}
// exclusive prefix of ecnt[0..7] up to e (replaces scan_kernel dispatch; uniform scalar loads)
__device__ __forceinline__ int eoff_of(const int* __restrict__ ecnt, int e) {
    int s = 0;
    #pragma unroll
    for (int i = 0; i < 8; i++) if (i < e) s += ecnt[i];
    return s;
}

// ================= GEMM core: 128x128 tile, BK=64, 4 waves (2x2), single-buffer =================
template<bool GATHER>
__device__ __forceinline__ void gemm_core(
        const u16* __restrict__ Ab, const u16* __restrict__ Bb,
        int m0, int n0, int Klen, int Ksa, int Ksb, int cnt, const int* __restrict__ idx,
        u16* lds_a, u16* lds_b, f32x4 (&acc)[4][4]) {
    const int tid = threadIdx.x;
    const int w = tid >> 6, l = tid & 63;
    const int c8 = l & 7, r8 = l >> 3;          // 16B chunk, row-within-8
    const int lr = l & 15, lg = l >> 4;
    const int wr = (w >> 1) * 64, wc = (w & 1) * 64;
    const int swz = (c8 ^ r8) << 4;             // inverse-swizzled source byte offset

    const char* asrc[4];
    const char* bsrc[4];
    #pragma unroll
    for (int i = 0; i < 4; i++) {
        int row = w * 32 + i * 8 + r8;          // tile row 0..127
        int gr = m0 + row; if (gr > cnt - 1) gr = cnt - 1;   // clamp partial tiles
        if (GATHER) gr = idx[gr];
        asrc[i] = (const char*)Ab + (size_t)gr * Ksa * 2 + swz;
        bsrc[i] = (const char*)Bb + (size_t)(n0 + row) * Ksb * 2 + swz;
    }
    for (int k0 = 0; k0 < Klen; k0 += 64) {
        __syncthreads();
        #pragma unroll
        for (int i = 0; i < 4; i++) {
            gload16(asrc[i] + (size_t)k0 * 2, lds_a + (w * 32 + i * 8) * 64);
            gload16(bsrc[i] + (size_t)k0 * 2, lds_b + (w * 32 + i * 8) * 64);
        }
        __syncthreads();
        #pragma unroll
        for (int kk = 0; kk < 2; kk++) {
            u16x8 af[4], bfr[4];
            #pragma unroll
            for (int mi = 0; mi < 4; mi++) {
                int m = wr + mi * 16 + lr;
                af[mi] = *(const u16x8*)((const char*)lds_a + m * 128 + (((kk * 4 + lg) ^ (m & 7)) << 4));
            }
            #pragma unroll
            for (int ni = 0; ni < 4; ni++) {
                int n = wc + ni * 16 + lr;
                bfr[ni] = *(const u16x8*)((const char*)lds_b + n * 128 + (((kk * 4 + lg) ^ (n & 7)) << 4));
            }
            #pragma unroll
            for (int mi = 0; mi < 4; mi++)
                #pragma unroll
                for (int ni = 0; ni < 4; ni++)
                    acc[mi][ni] = mfma_bf16(af[mi], bfr[ni], acc[mi][ni]);
        }
    }
}

// ================= coalesced bf16 epilogue: LDS-bounce (fixes 2x DRAM write amplification) ======
__device__ __forceinline__ void epilogue_bf16(
        f32x4 (&acc)[4][4], const float* __restrict__ bias, float sc, bool relu,
        u16* __restrict__ dst, int ldc, int m0, int n0, int cnt, u16* lds) {
    const int tid = threadIdx.x, w = tid >> 6, l = tid & 63;
    const int lr = l & 15, lg = l >> 4, wr = (w >> 1) * 64, wc = (w & 1) * 64;
    const int lrow_base = (wr ? 16 : 0);
    #pragma unroll
    for (int mi = 0; mi < 4; mi++) {
        __syncthreads();   // lds free of gemm_core readers (1st iter) / prior stores done
        #pragma unroll
        for (int ni = 0; ni < 4; ni++) {
            int col = wc + ni * 16 + lr;
            float bv = bias[n0 + col];
            #pragma unroll
            for (int r = 0; r < 4; r++) {
                float v = (acc[mi][ni][r] + bv) * sc;
                if (relu) v = fmaxf(v, 0.f);
                lds[(lrow_base + lg * 4 + r) * 132 + col] = f2bf(v);
            }
        }
        __syncthreads();
        int lrow = tid >> 3;                 // 0..31
        int lcol = (tid & 7) * 16;           // 0,16,...,112
        int grow = m0 + (lrow < 16 ? mi * 16 + lrow : 64 + mi * 16 + (lrow - 16));
        if (grow < cnt) {
            u16x8 v0 = *(const u16x8*)&lds[lrow * 132 + lcol];
            u16x8 v1 = *(const u16x8*)&lds[lrow * 132 + lcol + 8];
            *(u16x8*)&dst[(size_t)grow * ldc + n0 + lcol] = v0;
            *(u16x8*)&dst[(size_t)grow * ldc + n0 + lcol + 8] = v1;
        }
    }
}

// ================= dense GEMM: per-slab A/B/bias/out =================
struct Slab5 { const u16* a; const u16* bt; const float* bias; u16* cb; float sc; };
struct Slabs5 { Slab5 s[5]; };

template<int MODE, int NSLAB>
__global__ __launch_bounds__(256, 3) void gemm_dense(
        Slabs5 P, const float* __restrict__ extra, float* __restrict__ Cf, int K) {
    __shared__ __align__(16) u16 lds_a[128 * 64];
    __shared__ __align__(16) u16 lds_b[128 * 64];
    const int gx = NSLAB * 8;
    int bx, by;
    if (NSLAB == 5) {
        // 2D-chunked XCD mapping (r16). r17: co-residency breadth bounds L2 locality; kept (free).
        const int c = (int)blockIdx.x + gx * (int)blockIdx.y;
        const int b2 = c / 160, o = c % 160;
        bx = (b2 & 1) * 20 + (o % 20);
        by = (b2 >> 1) * 8 + (o / 20);
    } else {
        const int lid = swz_bid((int)blockIdx.x + gx * (int)blockIdx.y, gx * 32);
        bx = lid % gx; by = lid / gx;
    }
    const int slab = (NSLAB == 1) ? 0 : (bx >> 3);
    const int n0 = ((NSLAB == 1) ? bx : (bx & 7)) * 128;
    const int m0 = by * 128;
    f32x4 acc[4][4];
    #pragma unroll
    for (int i = 0; i < 4; i++)
        #pragma unroll
        for (int j = 0; j < 4; j++) acc[i][j] = (f32x4){0.f, 0.f, 0.f, 0.f};

    gemm_core<false>(P.s[slab].a, P.s[slab].bt, m0, n0, K, K, K, 0x7fffffff, nullptr, lds_a, lds_b, acc);

    if (MODE == 2) {
        epilogue_bf16(acc, P.s[slab].bias, P.s[slab].sc, false,
                      P.s[slab].cb, 1024, m0, n0, 0x7fffffff, lds_a);
        return;
    }
    const int tid = threadIdx.x, w = tid >> 6, l = tid & 63;
    const int lr = l & 15, lg = l >> 4, wr = (w >> 1) * 64, wc = (w & 1) * 64;
    const float* bias = P.s[slab].bias;
    #pragma unroll
    for (int ni = 0; ni < 4; ni++) {
        int col = n0 + wc + ni * 16 + lr;
        float bv = bias[col];
        #pragma unroll
        for (int mi = 0; mi < 4; mi++) {
            #pragma unroll
            for (int r = 0; r < 4; r++) {
                int row = m0 + wr + mi * 16 + lg * 4 + r;
                float v = acc[mi][ni][r] + bv;
                size_t off = (size_t)row * 1024 + col;
                Cf[off] = v + extra[off];
            }
        }
    }
}

// ================= MoE expert GEMMs (eoff computed inline from ecnt; scan dispatch removed) =====
__global__ __launch_bounds__(256, 3) void gemm_moe1(
        const u16* __restrict__ XNb, const u16* __restrict__ W1b, const float* __restrict__ b1,
        u16* __restrict__ HB, const int* __restrict__ eidx,
        const int* __restrict__ ecnt) {
    __shared__ __align__(16) u16 lds_a[128 * 64];
    __shared__ __align__(16) u16 lds_b[128 * 64];
    const int lid = swz_bid((int)blockIdx.x + 16 * ((int)blockIdx.y + 32 * (int)blockIdx.z), 4096);
    const int bx = lid & 15, rem = lid >> 4;
    const int by = rem & 31, e = rem >> 5;
    const int cnt = ecnt[e];
    const int m0 = by * 128;
    if (m0 >= cnt) return;
    const int n0 = bx * 128;    // N = 2048
    const int* idx = eidx + e * 4096;
    f32x4 acc[4][4];
    #pragma unroll
    for (int i = 0; i < 4; i++)
        #pragma unroll
        for (int j = 0; j < 4; j++) acc[i][j] = (f32x4){0.f, 0.f, 0.f, 0.f};

    gemm_core<true>(XNb, W1b + (size_t)e * 2048 * 1024, m0, n0, 1024, 1024, 1024, cnt, idx, lds_a, lds_b, acc);

    epilogue_bf16(acc, b1 + (size_t)e * 2048, 1.f, true,
                  HB + (size_t)eoff_of(ecnt, e) * 2048, 2048, m0, n0, cnt, lds_a);
}

// moe2: compact output Y[8192][1024] bf16 (no atomics); combine kernel applies gates.
__global__ __launch_bounds__(256, 3) void gemm_moe2(
        const u16* __restrict__ HB, const u16* __restrict__ W2b, const float* __restrict__ b2,
        u16* __restrict__ Y,
        const int* __restrict__ ecnt) {
    __shared__ __align__(16) u16 lds_a[128 * 64];
    __shared__ __align__(16) u16 lds_b[128 * 64];
    const int lid = swz_bid((int)blockIdx.x + 8 * ((int)blockIdx.y + 32 * (int)blockIdx.z), 2048);
    const int bx = lid & 7, rem = lid >> 3;
    const int by = rem & 31, e = rem >> 5;
    const int cnt = ecnt[e];
    const int m0 = by * 128;
    if (m0 >= cnt) return;
    const int n0 = bx * 128;    // N = 1024
    const int eo = eoff_of(ecnt, e);
    const u16* Ae = HB + (size_t)eo * 2048;
    f32x4 acc[4][4];
    #pragma unroll
    for (int i = 0; i < 4; i++)
        #pragma unroll
        for (int j = 0; j < 4; j++) acc[i][j] = (f32x4){0.f, 0.f, 0.f, 0.f};

    gemm_core<false>(Ae, W2b + (size_t)e * 1024 * 2048, m0, n0, 2048, 2048, 2048, cnt, nullptr, lds_a, lds_b, acc);

    epilogue_bf16(acc, b2 + (size_t)e * 1024, 1.f, false,
                  Y + (size_t)eo * 1024, 1024, m0, n0, cnt, lds_a);
}

// combine: out[t] += g0*Y[slot0[t]] + g1*Y[slot1[t]]  (prefix of ecnt computed inline)
__global__ void combine_kernel(const float* __restrict__ g2, const int* __restrict__ slotmap,
                               const int* __restrict__ ecnt, const u16* __restrict__ Y,
                               float* __restrict__ out) {
    int eo[8];
    {
        int s = 0;
        #pragma unroll
        for (int e = 0; e < 8; e++) { eo[e] = s; s += ecnt[e]; }
    }
    int t = blockIdx.x * 4 + (threadIdx.x >> 6);
    int l = threadIdx.x & 63;
    int s0 = slotmap[t * 2], s1 = slotmap[t * 2 + 1];
    float g0 = g2[t * 2], g1 = g2[t * 2 + 1];
    int r0 = eo[s0 >> 16] + (s0 & 0xffff);
    int r1 = eo[s1 >> 16] + (s1 & 0xffff);
    const u16* y0 = Y + (size_t)r0 * 1024 + l * 16;
    const u16* y1 = Y + (size_t)r1 * 1024 + l * 16;
    float* op = out + (size_t)t * 1024 + l * 16;
    u16x8 a0 = *(const u16x8*)y0;
    u16x8 a1 = *(const u16x8*)(y0 + 8);
    u16x8 b0 = *(const u16x8*)y1;
    u16x8 b1 = *(const u16x8*)(y1 + 8);
    f32x4 o[4];
    #pragma unroll
    for (int j = 0; j < 4; j++) o[j] = *(const f32x4*)(op + j * 4);
    #pragma unroll
    for (int j = 0; j < 4; j++) {
        o[0][j] += g0 * bf2f(a0[j])     + g1 * bf2f(b0[j]);
        o[1][j] += g0 * bf2f(a0[j + 4]) + g1 * bf2f(b0[j + 4]);
        o[2][j] += g0 * bf2f(a1[j])     + g1 * bf2f(b1[j]);
        o[3][j] += g0 * bf2f(a1[j + 4]) + g1 * bf2f(b1[j + 4]);
    }
    #pragma unroll
    for (int j = 0; j < 4; j++) *(f32x4*)(op + j * 4) = o[j];
}

// ================= LayerNorm (ln1/ln2: bf16 out) =================
__global__ void ln_kernel(const float* __restrict__ X, const float* __restrict__ g,
                          const float* __restrict__ bt, u16* __restrict__ Yb) {
    int row = blockIdx.x * 4 + (threadIdx.x >> 6);
    int l = threadIdx.x & 63;
    const float* x = X + (size_t)row * 1024;
    f32x4 v[4];
    float s = 0.f, s2 = 0.f;
    #pragma unroll
    for (int i = 0; i < 4; i++) {
        v[i] = *reinterpret_cast<const f32x4*>(x + i * 256 + l * 4);
        #pragma unroll
        for (int j = 0; j < 4; j++) { s += v[i][j]; s2 += v[i][j] * v[i][j]; }
    }
    #pragma unroll
    for (int m = 1; m < 64; m <<= 1) { s += __shfl_xor(s, m); s2 += __shfl_xor(s2, m); }
    float mu = s * (1.f / 1024.f);
    float var = s2 * (1.f / 1024.f) - mu * mu;
    float rs = rsqrtf(var + 1e-5f);
    #pragma unroll
    for (int i = 0; i < 4; i++) {
        f32x4 gv = *reinterpret_cast<const f32x4*>(g + i * 256 + l * 4);
        f32x4 bv = *reinterpret_cast<const f32x4*>(bt + i * 256 + l * 4);
        u16x4 ob;
        #pragma unroll
        for (int j = 0; j < 4; j++) ob[j] = f2bf((v[i][j] - mu) * rs * gv[j] + bv[j]);
        *reinterpret_cast<u16x4*>(Yb + (size_t)row * 1024 + i * 256 + l * 4) = ob;
    }
}

// ================= ln3 fused with gate: bf16 out + fp64-accum top-2 routing =================
__global__ void ln_gate_kernel(const float* __restrict__ X, const float* __restrict__ g,
                               const float* __restrict__ bt, u16* __restrict__ Yb,
                               const float* __restrict__ GW,
                               float* __restrict__ g2, int* __restrict__ top2) {
    int row = blockIdx.x * 4 + (threadIdx.x >> 6);
    int l = threadIdx.x & 63;
    const float* x = X + (size_t)row * 1024;
    f32x4 v[4];
    float s = 0.f, s2 = 0.f;
    #pragma unroll
    for (int i = 0; i < 4; i++) {
        v[i] = *reinterpret_cast<const f32x4*>(x + i * 256 + l * 4);
        #pragma unroll
        for (int j = 0; j < 4; j++) { s += v[i][j]; s2 += v[i][j] * v[i][j]; }
    }
    #pragma unroll
    for (int m = 1; m < 64; m <<= 1) { s += __shfl_xor(s, m); s2 += __shfl_xor(s2, m); }
    float mu = s * (1.f / 1024.f);
    float var = s2 * (1.f / 1024.f) - mu * mu;
    float rs = rsqrtf(var + 1e-5f);
    double p[8] = {0, 0, 0, 0, 0, 0, 0, 0};
    #pragma unroll
    for (int i = 0; i < 4; i++) {
        f32x4 gv = *reinterpret_cast<const f32x4*>(g + i * 256 + l * 4);
        f32x4 bv = *reinterpret_cast<const f32x4*>(bt + i * 256 + l * 4);
        u16x4 ob;
        #pragma unroll
        for (int j = 0; j < 4; j++) {
            float o = (v[i][j] - mu) * rs * gv[j] + bv[j];
            ob[j] = f2bf(o);
            const float* gw = GW + (size_t)(i * 256 + l * 4 + j) * 8;
            #pragma unroll
            for (int e = 0; e < 8; e++) p[e] += (double)o * (double)gw[e];
        }
        *reinterpret_cast<u16x4*>(Yb + (size_t)row * 1024 + i * 256 + l * 4) = ob;
    }
    #pragma unroll
    for (int e = 0; e < 8; e++) {
        #pragma unroll
        for (int m = 1; m < 64; m <<= 1) p[e] += __shfl_xor(p[e], m);
    }
    if (l == 0) {
        int i0 = 0; double v0 = p[0];
        #pragma unroll
        for (int e = 1; e < 8; e++) if (p[e] > v0) { v0 = p[e]; i0 = e; }
        int i1 = -1; double v1 = -1e300;
        #pragma unroll
        for (int e = 0; e < 8; e++) if (e != i0 && p[e] > v1) { v1 = p[e]; i1 = e; }
        float ex = __expf((float)(v1 - v0));
        float ga = 1.f / (1.f + ex);
        float gb = ex * ga;
        g2[row * 2] = ga; g2[row * 2 + 1] = gb;
        top2[row] = i0 | (i1 << 8);
    }
}

// ================= weight transpose+convert =================
struct Ptr8 { const float* p[8]; };
__global__ void wtrans_kernel(Ptr8 srcs, u16* __restrict__ dst, int K, int N) {
    __shared__ float t[64][65];
    const float* W = srcs.p[blockIdx.z];
    u16* Wt = dst + (size_t)blockIdx.z * K * N;
    int k0 = blockIdx.y * 64, n0 = blockIdx.x * 64;
    int tx = threadIdx.x, ty = threadIdx.y;
    #pragma unroll
    for (int i = 0; i < 8; i++) t[ty + i * 8][tx] = W[(size_t)(k0 + ty + i * 8) * N + n0 + tx];
    __syncthreads();
    #pragma unroll
    for (int i = 0; i < 8; i++) Wt[(size_t)(n0 + ty + i * 8) * K + k0 + tx] = f2bf(t[tx][ty + i * 8]);
}

// ================= flat fp32 -> bf16 =================
__global__ void cvt_kernel(const float* __restrict__ s, u16* __restrict__ d, int n) {
    int i = ((int)blockIdx.x * 256 + (int)threadIdx.x) * 8;
    if (i >= n) return;
    f32x4 a = *reinterpret_cast<const f32x4*>(s + i);
    f32x4 b = *reinterpret_cast<const f32x4*>(s + i + 4);
    u16x8 h;
    h[0] = f2bf(a[0]); h[1] = f2bf(a[1]); h[2] = f2bf(a[2]); h[3] = f2bf(a[3]);
    h[4] = f2bf(b[0]); h[5] = f2bf(b[1]); h[6] = f2bf(b[2]); h[7] = f2bf(b[3]);
    *reinterpret_cast<u16x8*>(d + i) = h;
}

// ================= V transpose (bf16) =================
__global__ void transpose_v(const u16* __restrict__ V, u16* __restrict__ Vt) {
    __shared__ u16 tile[32][34];
    int s0 = blockIdx.x * 32;
    int d0 = blockIdx.y * 32;
    int bh = blockIdx.z;
    int b = bh >> 4, h = bh & 15;
    int tx = threadIdx.x, ty = threadIdx.y;
    #pragma unroll
    for (int i = 0; i < 4; i++) {
        int s = s0 + ty + i * 8;
        tile[ty + i * 8][tx] = V[((size_t)s * 4 + b) * 1024 + h * 64 + d0 + tx];
    }
    __syncthreads();
    #pragma unroll
    for (int i = 0; i < 4; i++) {
        int d = d0 + ty + i * 8;
        Vt[((size_t)(bh * 64 + d)) * 1024 + s0 + tx] = tile[tx][ty + i * 8];
    }
}

// ================= flash attention (r16 body; attn is at its structural plateau) =================
template<bool CAUSAL>
__global__ __launch_bounds__(256, 4) void attn_kernel(
        const u16* __restrict__ Q, const u16* __restrict__ Km,
        const u16* __restrict__ Vt, u16* __restrict__ O) {
    __shared__ __align__(16) u16 kt_lds[64 * 64];
    __shared__ __align__(16) u16 vt_lds[64 * 64];
    __shared__ __align__(16) u16 p_lds[4][16 * 68];

    const int lid = swz_bid((int)blockIdx.x, 1024);
    int qt;
    if (CAUSAL) {
        const int i = lid & 15, j = (lid >> 5) & 3;
        qt = (((j & 1) ? (15 - i) : i) + ((j >> 1) << 3)) & 15;
    } else {
        qt = lid & 15;
    }
    const int hh = (lid >> 4) & 15;
    const int b  = lid >> 8;
    const int tid = threadIdx.x;
    const int w = tid >> 6, l = tid & 63;
    const int lr = l & 15, lg = l >> 4;
    const int c8 = l & 7, r8 = l >> 3;
    const int qb = qt * 64;

    u16x8 qf0, qf1;
    {
        const u16* qp = Q + ((size_t)(qb + w * 16 + lr) * 4 + b) * 1024 + hh * 64 + lg * 8;
        qf0 = *(const u16x8*)qp;
        qf1 = *(const u16x8*)(qp + 32);
    }
    const u16* kbase = Km + (size_t)b * 1024 + (size_t)hh * 64 + ((c8 ^ r8) << 3);
    const u16* vbase = Vt + ((size_t)(b * 16 + hh) * 64) * 1024 + ((c8 ^ r8) << 3);

    f32x4 o[4];
    #pragma unroll
    for (int ni = 0; ni < 4; ni++) o[ni] = (f32x4){0.f, 0.f, 0.f, 0.f};
    float Mr[4], Lr[4];
    #pragma unroll
    for (int r = 0; r < 4; r++) { Mr[r] = -1e30f; Lr[r] = 0.f; }

    const int nkt = CAUSAL ? (qt + 1) : 16;

    for (int kt = 0; kt < nkt; ++kt) {
        __syncthreads();   // all waves done reading previous tile
        #pragma unroll
        for (int i = 0; i < 2; i++) {
            int rrow = w * 16 + i * 8 + r8;
            gload16(kbase + (size_t)(kt * 64 + rrow) * 4096, &kt_lds[(w * 16 + i * 8) * 64]);
            gload16(vbase + (size_t)rrow * 1024 + kt * 64, &vt_lds[(w * 16 + i * 8) * 64]);
        }
        __syncthreads();   // implicit vmcnt(0) drain: tile ready

        f32x4 s4[4];
        __builtin_amdgcn_s_setprio(1);
        #pragma unroll
        for (int g = 0; g < 4; g++) {
            int krow = g * 16 + lr;
            const char* kl = (const char*)kt_lds + krow * 128;
            u16x8 kf0 = *(const u16x8*)(kl + ((lg ^ (krow & 7)) << 4));
            u16x8 kf1 = *(const u16x8*)(kl + (((lg + 4) ^ (krow & 7)) << 4));
            s4[g] = mfma_bf16(qf0, kf0, (f32x4){0.f, 0.f, 0.f, 0.f});
            s4[g] = mfma_bf16(qf1, kf1, s4[g]);
        }
        __builtin_amdgcn_s_setprio(0);
        if (CAUSAL && kt == qt) {
            #pragma unroll
            for (int g = 0; g < 4; g++) {
                int kg = kt * 64 + g * 16 + lr;
                #pragma unroll
                for (int r = 0; r < 4; r++) {
                    int qg = qb + w * 16 + lg * 4 + r;
                    if (kg > qg) s4[g][r] = -1e30f;
                }
            }
        }
        float mx[4];
        #pragma unroll
        for (int r = 0; r < 4; r++) {
            float m_ = fmaxf(fmaxf(s4[0][r], s4[1][r]), fmaxf(s4[2][r], s4[3][r]));
            m_ = fmaxf(m_, __shfl_xor(m_, 1));
            m_ = fmaxf(m_, __shfl_xor(m_, 2));
            m_ = fmaxf(m_, __shfl_xor(m_, 4));
            m_ = fmaxf(m_, __shfl_xor(m_, 8));
            mx[r] = m_;
        }
        bool fast = __all((mx[0] <= Mr[0] + 8.f) && (mx[1] <= Mr[1] + 8.f) &&
                          (mx[2] <= Mr[2] + 8.f) && (mx[3] <= Mr[3] + 8.f));
        #pragma unroll
        for (int r = 0; r < 4; r++) {
            if (!fast) {
                float newM = fmaxf(Mr[r], mx[r]);
                float corr = __expf(Mr[r] - newM);
                Lr[r] *= corr;
                o[0][r] *= corr; o[1][r] *= corr; o[2][r] *= corr; o[3][r] *= corr;
                Mr[r] = newM;
            }
            float p0 = __expf(s4[0][r] - Mr[r]);
            float p1 = __expf(s4[1][r] - Mr[r]);
            float p2 = __expf(s4[2][r] - Mr[r]);
            float p3 = __expf(s4[3][r] - Mr[r]);
            float ps = (p0 + p1) + (p2 + p3);
            ps += __shfl_xor(ps, 1); ps += __shfl_xor(ps, 2);
            ps += __shfl_xor(ps, 4); ps += __shfl_xor(ps, 8);
            Lr[r] += ps;
            int prow = lg * 4 + r;
            p_lds[w][prow * 68 + lr] = f2bf(p0);
            p_lds[w][prow * 68 + 16 + lr] = f2bf(p1);
            p_lds[w][prow * 68 + 32 + lr] = f2bf(p2);
            p_lds[w][prow * 68 + 48 + lr] = f2bf(p3);
        }
        asm volatile("s_waitcnt lgkmcnt(0)" ::: "memory");
        __builtin_amdgcn_s_setprio(1);
        #pragma unroll
        for (int kk = 0; kk < 2; kk++) {
            u16x8 pf = *(const u16x8*)&p_lds[w][lr * 68 + kk * 32 + lg * 8];
            #pragma unroll
            for (int ni = 0; ni < 4; ni++) {
                int vrow = ni * 16 + lr;
                const char* vl = (const char*)vt_lds + vrow * 128;
                u16x8 vf = *(const u16x8*)(vl + (((kk * 4 + lg) ^ (vrow & 7)) << 4));
                o[ni] = mfma_bf16(pf, vf, o[ni]);
            }
        }
        __builtin_amdgcn_s_setprio(0);
    }
    #pragma unroll
    for (int ni = 0; ni < 4; ni++) {
        #pragma unroll
        for (int r = 0; r < 4; r++) {
            int row = qb + w * 16 + lg * 4 + r;
            int col = ni * 16 + lr;
            O[((size_t)row * 4 + b) * 1024 + hh * 64 + col] = f2bf(o[ni][r] / Lr[r]);
        }
    }
}

// ================= build per-expert token lists + slot map =================
__global__ void build_lists(const int* __restrict__ top2, int* __restrict__ eidx,
                            int* __restrict__ ecnt, int* __restrict__ slotmap) {
    const int e = blockIdx.x;           // 8 blocks, one per expert
    const int tid = threadIdx.x;        // 256
    const int w = tid >> 6, l = tid & 63;
    __shared__ int wcnt[4];
    int base = 0;                       // maintained uniformly by all threads
    for (int c = 0; c < 4096; c += 256) {
        int tok = c + tid;
        int t2 = top2[tok];
        bool pf = ((t2 & 0xff) == e);
        bool ps = (((t2 >> 8) & 0xff) == e);
        bool pred = pf || ps;
        unsigned long long mask = __ballot(pred);
        if (l == 0) wcnt[w] = __popcll(mask);
        __syncthreads();
        int wb = base;
        for (int i = 0; i < w; i++) wb += wcnt[i];
        int pos = __popcll(mask & ((1ull << l) - 1ull));
        if (pred) {
            eidx[e * 4096 + wb + pos] = tok;
            slotmap[tok * 2 + (pf ? 0 : 1)] = (e << 16) | (wb + pos);
        }
        base += wcnt[0] + wcnt[1] + wcnt[2] + wcnt[3];
        __syncthreads();                // protect wcnt for next chunk
    }
    if (tid == 0) ecnt[e] = base;
}

// ================= launch =================
extern "C" void kernel_launch(void* const* d_in, const int* in_sizes, int n_in,
                              void* d_out, int out_size, void* d_ws, size_t ws_size,
                              hipStream_t stream) {
    const float* x    = (const float*)d_in[0];
    const float* enc  = (const float*)d_in[1];
    const float* ln1g = (const float*)d_in[3];
    const float* ln1b = (const float*)d_in[4];
    const float* ln2g = (const float*)d_in[5];
    const float* ln2b = (const float*)d_in[6];
    const float* ln3g = (const float*)d_in[7];
    const float* ln3b = (const float*)d_in[8];
    const float* saWq = (const float*)d_in[9];  const float* sabq = (const float*)d_in[10];
    const float* saWk = (const float*)d_in[11]; const float* sabk = (const float*)d_in[12];
    const float* saWv = (const float*)d_in[13]; const float* sabv = (const float*)d_in[14];
    const float* saWo = (const float*)d_in[15]; const float* sabo = (const float*)d_in[16];
    const float* caWq = (const float*)d_in[17]; const float* cabq = (const float*)d_in[18];
    const float* caWk = (const float*)d_in[19]; const float* cabk = (const float*)d_in[20];
    const float* caWv = (const float*)d_in[21]; const float* cabv = (const float*)d_in[22];
    const float* caWo = (const float*)d_in[23]; const float* cabo = (const float*)d_in[24];
    const float* gateW = (const float*)d_in[25];
    const float* W1 = (const float*)d_in[26]; const float* b1 = (const float*)d_in[27];
    const float* W2 = (const float*)d_in[28]; const float* b2 = (const float*)d_in[29];
    float* out = (float*)d_out;
    char* W = (char*)d_ws;

    const size_t MB = 1ull << 20;
    u16*   Wattn = (u16*)(W);                 // 0..16MB : 8 x [1024][1024] bf16 (B^T)
    u16*   Qb    = (u16*)(W + 16 * MB);       // 8MB
    u16*   Kb    = (u16*)(W + 24 * MB);       // 8MB
    u16*   Vb    = (u16*)(W + 32 * MB);       // 8MB
    u16*   VTb   = (u16*)(W + 40 * MB);       // 8MB
    u16*   ATb   = (u16*)(W + 48 * MB);       // 8MB
    u16*   encb  = (u16*)(W + 56 * MB);       // 8MB
    u16*   XNb   = (u16*)(W + 64 * MB);       // 8MB
    float* X1    = (float*)(W + 72 * MB);     // 16MB fp32 (SA residual out)
    u16*   K2b   = (u16*)(W + 88 * MB);       // 8MB (CA K; HB overlays later)
    u16*   V2b   = (u16*)(W + 96 * MB);       // 8MB (CA V)
    u16*   HB    = (u16*)(W + 88 * MB);       // 32MB: compact expert hidden (overlays K2b/V2b after CA)
    u16*   W1b   = (u16*)(W);                 // MoE: 0..32MB (overlays Wattn,Qb,Kb after CA-O)
    u16*   W2b   = (u16*)(W + 32 * MB);       // MoE: 32..64MB (overlays Vb,VTb,ATb,encb)
    u16*   Yc    = (u16*)(W);                 // 16MB compact moe2 out (overlays W1b, dead after moe1)
    float* g2    = (float*)(W + 120 * MB);              // 32KB (4096 x 2)
    int*   eidx  = (int*)(W + 120 * MB + 128 * 1024);   // 128KB
    int*   ecnt  = (int*)(W + 120 * MB + 256 * 1024);   // 64B
    int*   top2  = (int*)(W + 120 * MB + 272 * 1024);   // 16KB
    int*   slotmap = (int*)(W + 120 * MB + 320 * 1024); // 32KB

    dim3 bw(64, 8);
    const float SC = 0.125f;   // 1/sqrt(64) — power of two: lossless bf16 Q prescale (r12 lesson)

    {
        Ptr8 p; p.p[0]=saWq; p.p[1]=saWk; p.p[2]=saWv; p.p[3]=saWo;
                p.p[4]=caWq; p.p[5]=caWk; p.p[6]=caWv; p.p[7]=caWo;
        wtrans_kernel<<<dim3(16, 16, 8), bw, 0, stream>>>(p, Wattn, 1024, 1024);
    }
    cvt_kernel<<<2048, 256, 0, stream>>>(enc, encb, 4096 * 1024);

    // ---- self-attn QKV + cross-attn KV batched: 5 slabs, 1280 blocks (5/CU) ----
    ln_kernel<<<1024, 256, 0, stream>>>(x, ln1g, ln1b, XNb);
    {
        Slabs5 P;
        P.s[0] = {XNb,  Wattn,               sabq, Qb,  SC };
        P.s[1] = {XNb,  Wattn + 1 * 1048576, sabk, Kb,  1.f};
        P.s[2] = {XNb,  Wattn + 2 * 1048576, sabv, Vb,  1.f};
        P.s[3] = {encb, Wattn + 5 * 1048576, cabk, K2b, 1.f};
        P.s[4] = {encb, Wattn + 6 * 1048576, cabv, V2b, 1.f};
        gemm_dense<2, 5><<<dim3(40, 32), 256, 0, stream>>>(P, nullptr, nullptr, 1024);
    }
    transpose_v<<<dim3(32, 2, 64), dim3(32, 8), 0, stream>>>(Vb, VTb);
    attn_kernel<true><<<1024, 256, 0, stream>>>(Qb, Kb, VTb, ATb);
    {
        Slabs5 P; P.s[0] = {ATb, Wattn + 3 * 1048576, sabo, nullptr, 1.f};
        gemm_dense<1, 1><<<dim3(8, 32), 256, 0, stream>>>(P, x, X1, 1024);
    }

    // ---- cross-attention ----
    ln_kernel<<<1024, 256, 0, stream>>>(X1, ln2g, ln2b, XNb);
    {
        Slabs5 P; P.s[0] = {XNb, Wattn + 4 * 1048576, cabq, Qb, SC};
        gemm_dense<2, 1><<<dim3(8, 32), 256, 0, stream>>>(P, nullptr, nullptr, 1024);
    }
    transpose_v<<<dim3(32, 2, 64), dim3(32, 8), 0, stream>>>(V2b, VTb);
    attn_kernel<false><<<1024, 256, 0, stream>>>(Qb, K2b, VTb, ATb);
    {
        Slabs5 P; P.s[0] = {ATb, Wattn + 7 * 1048576, cabo, nullptr, 1.f};
        gemm_dense<1, 1><<<dim3(8, 32), 256, 0, stream>>>(P, X1, out, 1024);
    }

    // ---- MoE ----
    {
        Ptr8 p1; for (int e = 0; e < 8; e++) p1.p[e] = W1 + (size_t)e * 1024 * 2048;
        wtrans_kernel<<<dim3(32, 16, 8), bw, 0, stream>>>(p1, W1b, 1024, 2048);
        Ptr8 p2; for (int e = 0; e < 8; e++) p2.p[e] = W2 + (size_t)e * 2048 * 1024;
        wtrans_kernel<<<dim3(16, 32, 8), bw, 0, stream>>>(p2, W2b, 2048, 1024);
    }
    ln_gate_kernel<<<1024, 256, 0, stream>>>(out, ln3g, ln3b, XNb, gateW, g2, top2);
    build_lists<<<8, 256, 0, stream>>>(top2, eidx, ecnt, slotmap);
    gemm_moe1<<<dim3(16, 32, 8), 256, 0, stream>>>(XNb, W1b, b1, HB, eidx, ecnt);
    gemm_moe2<<<dim3(8, 32, 8), 256, 0, stream>>>(HB, W2b, b2, Yc, ecnt);
    combine_kernel<<<1024, 256, 0, stream>>>(g2, slotmap, ecnt, Yc, out);
}